// Round 4
// baseline (3141.348 us; speedup 1.0000x reference)
//
#include <hip/hip_runtime.h>
#include <stdint.h>

// BinHD: samples [8192,10000] f32 {0,1}, classes [1000,10000] f32 {0,1}
// out [8192,1000] f32 = Hamming = popcount(xor) over bit-packed rows (exact).
#define N_ROWS 8192
#define C_CLS  1000
#define D_DIM  10000
#define W64P   160            // u64 words per packed row, padded (157 used)
#define W32P   (W64P * 2)     // 320 u32 words per packed row
#define NCHUNK 20             // 20 chunks x 16 u32 words = 320

// async global->LDS, 16B per lane. LDS dest = wave-uniform base + lane*16.
__device__ __forceinline__ void gl2lds16(const uint32_t* g, uint32_t* l) {
    __builtin_amdgcn_global_load_lds(
        (const __attribute__((address_space(1))) void*)g,
        (__attribute__((address_space(3))) void*)l, 16, 0, 0);
}

// ---------------------------------------------------------------------------
// Kernel 1: bit-pack via float4 + 4 wave ballots. One wave per row.
// ---------------------------------------------------------------------------
__global__ __launch_bounds__(256) void pack_kernel(
    const float* __restrict__ samples, const float* __restrict__ classes,
    unsigned long long* __restrict__ pA, unsigned long long* __restrict__ pB)
{
    int gwave = (blockIdx.x * 256 + threadIdx.x) >> 6;
    int lane  = threadIdx.x & 63;
    if (gwave >= N_ROWS + C_CLS) return;   // wave-uniform exit

    const float* src;
    unsigned long long* dst;
    if (gwave < N_ROWS) {
        src = samples + (size_t)gwave * D_DIM;
        dst = pA + (size_t)gwave * W64P;
    } else {
        int r = gwave - N_ROWS;
        src = classes + (size_t)r * D_DIM;
        dst = pB + (size_t)r * W64P;
    }

    #pragma unroll 4
    for (int it = 0; it < 39; ++it) {       // dims 0..9983 -> words 0..155
        float4 v = *(const float4*)(src + it * 256 + lane * 4);
        unsigned long long m0 = __ballot(v.x > 0.5f);
        unsigned long long m1 = __ballot(v.y > 0.5f);
        unsigned long long m2 = __ballot(v.z > 0.5f);
        unsigned long long m3 = __ballot(v.w > 0.5f);
        if (lane < 2) {
            ulonglong2 st;
            st.x = lane ? m2 : m0;
            st.y = lane ? m3 : m1;
            *(ulonglong2*)(dst + it * 4 + lane * 2) = st;
        }
    }
    {   // tail: dims 9984..9999 -> words 156..159 (zero-padded)
        float4 v = make_float4(0.f, 0.f, 0.f, 0.f);
        if (lane < 4) v = *(const float4*)(src + 9984 + lane * 4);
        unsigned long long m0 = __ballot(v.x > 0.5f);
        unsigned long long m1 = __ballot(v.y > 0.5f);
        unsigned long long m2 = __ballot(v.z > 0.5f);
        unsigned long long m3 = __ballot(v.w > 0.5f);
        if (lane < 2) {
            ulonglong2 st;
            st.x = lane ? m2 : m0;
            st.y = lane ? m3 : m1;
            *(ulonglong2*)(dst + 156 + lane * 2) = st;
        }
    }
}

// ---------------------------------------------------------------------------
// Kernel 2: Hamming GEMM. 128x128 tile, 256 thr, 8x8 acc/thread.
// Double-buffered LDS; staging via async global_load_lds (NO staging VGPRs,
// NO staging stores — R3's register prefetch spilled acc[] to scratch).
// Both A and B in LDS as [row][16 words], 16B-granule XOR-swizzled by
// (row>>3)&3. Swizzle realized on the GLOBAL side: lane gathers the granule
// that belongs at its fixed LDS slot (base + lane*16).
// One barrier per chunk; __syncthreads drains vmcnt (async loads done).
// ---------------------------------------------------------------------------
__global__ __launch_bounds__(256) void hd_kernel(
    const uint32_t* __restrict__ pA, const uint32_t* __restrict__ pB,
    float* __restrict__ out)
{
    __shared__ __attribute__((aligned(16))) uint32_t As[2][128 * 16];
    __shared__ __attribute__((aligned(16))) uint32_t Bs[2][128 * 16];

    const int tid  = threadIdx.x;
    const int row0 = blockIdx.x * 128;
    const int col0 = blockIdx.y * 128;

    const int w    = tid >> 6;
    const int lane = tid & 63;
    const int lx   = lane & 7;
    const int ly   = lane >> 3;
    const int wx   = w & 1, wy = w >> 1;
    const int trow = wy * 64 + ly * 8;       // thread row base in 128-tile
    const int tcol = wx * 64 + lx * 4;       // thread col base (dense mapping)
    const int ka   = (trow >> 3) & 3;        // A read swizzle key
    const int kb   = (tcol >> 3) & 3;        // B read swizzle key (same for tcol+32)

    // ---- staging addresses: wave w, instrs j=0,1; slot s = w*128 + j*64 + lane
    const int s0   = w * 128 + lane;
    const int s1   = s0 + 64;
    const int rr0  = s0 >> 2, rr1 = s1 >> 2;               // tile row/col 0..127
    const int gg0  = (s0 & 3) ^ ((rr0 >> 3) & 3);          // permuted granule
    const int gg1  = (s1 & 3) ^ ((rr1 >> 3) & 3);
    const uint32_t* gA0 = pA + (size_t)(row0 + rr0) * W32P + gg0 * 4;
    const uint32_t* gA1 = pA + (size_t)(row0 + rr1) * W32P + gg1 * 4;
    const bool okB0 = (col0 + rr0) < C_CLS;
    const bool okB1 = (col0 + rr1) < C_CLS;
    const uint32_t* gB0 = pB + (size_t)(okB0 ? (col0 + rr0) : 0) * W32P + gg0 * 4;
    const uint32_t* gB1 = pB + (size_t)(okB1 ? (col0 + rr1) : 0) * W32P + gg1 * 4;
    // LDS bases (wave-uniform): instr j of wave w -> word offset w*512 + j*256
    const int ldsA = w * 512;

    uint32_t acc[8][8];
    #pragma unroll
    for (int r = 0; r < 8; ++r)
        #pragma unroll
        for (int c = 0; c < 8; ++c) acc[r][c] = 0;

    // ---- prologue: stage chunk 0 -> buf 0 ----
    gl2lds16(gA0, &As[0][ldsA]);
    gl2lds16(gA1, &As[0][ldsA + 256]);
    if (okB0) gl2lds16(gB0, &Bs[0][ldsA]);
    if (okB1) gl2lds16(gB1, &Bs[0][ldsA + 256]);
    __syncthreads();

    for (int ch = 0; ch < NCHUNK; ++ch) {
        const int cur = ch & 1;
        const int nxt = cur ^ 1;

        // ---- async-stage chunk ch+1 into buf[nxt] (in flight across compute)
        if (ch + 1 < NCHUNK) {
            const int off = (ch + 1) * 16;
            gl2lds16(gA0 + off, &As[nxt][ldsA]);
            gl2lds16(gA1 + off, &As[nxt][ldsA + 256]);
            if (okB0) gl2lds16(gB0 + off, &Bs[nxt][ldsA]);
            if (okB1) gl2lds16(gB1 + off, &Bs[nxt][ldsA + 256]);
        }

        // ---- compute chunk ch from buf[cur] ----
        #pragma unroll
        for (int g = 0; g < 4; ++g) {
            uint4 a[8];
            #pragma unroll
            for (int r = 0; r < 8; ++r)
                a[r] = *(const uint4*)&As[cur][(trow + r) * 16 + ((g ^ ka) << 2)];

            uint4 b[4];
            #pragma unroll
            for (int cc = 0; cc < 4; ++cc)
                b[cc] = *(const uint4*)&Bs[cur][(tcol + cc) * 16 + ((g ^ kb) << 2)];
            #pragma unroll
            for (int r = 0; r < 8; ++r) {
                #pragma unroll
                for (int cc = 0; cc < 4; ++cc) {
                    acc[r][cc] += __popc(a[r].x ^ b[cc].x) + __popc(a[r].y ^ b[cc].y)
                                + __popc(a[r].z ^ b[cc].z) + __popc(a[r].w ^ b[cc].w);
                }
            }
            #pragma unroll
            for (int cc = 0; cc < 4; ++cc)
                b[cc] = *(const uint4*)&Bs[cur][(tcol + 32 + cc) * 16 + ((g ^ kb) << 2)];
            #pragma unroll
            for (int r = 0; r < 8; ++r) {
                #pragma unroll
                for (int cc = 0; cc < 4; ++cc) {
                    acc[r][cc + 4] += __popc(a[r].x ^ b[cc].x) + __popc(a[r].y ^ b[cc].y)
                                    + __popc(a[r].z ^ b[cc].z) + __popc(a[r].w ^ b[cc].w);
                }
            }
        }

        __syncthreads();   // drains vmcnt (staging done) + lgkm; buffers swap
    }

    // ---- epilogue: dense float4 stores (lane-contiguous 128B lines) ----
    #pragma unroll
    for (int r = 0; r < 8; ++r) {
        int grow = row0 + trow + r;
        #pragma unroll
        for (int c4 = 0; c4 < 2; ++c4) {
            int gcol = col0 + tcol + c4 * 32;
            if (gcol < C_CLS) {
                float4 v = make_float4((float)acc[r][c4 * 4 + 0],
                                       (float)acc[r][c4 * 4 + 1],
                                       (float)acc[r][c4 * 4 + 2],
                                       (float)acc[r][c4 * 4 + 3]);
                *(float4*)(out + (size_t)grow * C_CLS + gcol) = v;
            }
        }
    }
}

extern "C" void kernel_launch(void* const* d_in, const int* in_sizes, int n_in,
                              void* d_out, int out_size, void* d_ws, size_t ws_size,
                              hipStream_t stream) {
    const float* samples = (const float*)d_in[0];   // [8192, 10000] f32
    const float* classes = (const float*)d_in[1];   // [1000, 10000] f32
    float* out = (float*)d_out;                     // [8192, 1000] f32

    unsigned long long* pA = (unsigned long long*)d_ws;          // 10.49 MB
    unsigned long long* pB = pA + (size_t)N_ROWS * W64P;         // +1.28 MB

    int waves  = N_ROWS + C_CLS;
    int blocks = (waves + 3) / 4;
    pack_kernel<<<blocks, 256, 0, stream>>>(samples, classes, pA, pB);

    dim3 grid(N_ROWS / 128, 8);              // 64 x 8 = 512 blocks (2/CU)
    hd_kernel<<<grid, 256, 0, stream>>>((const uint32_t*)pA, (const uint32_t*)pB, out);
}

// Round 5
// 1083.235 us; speedup vs baseline: 2.9000x; 2.9000x over previous
//
#include <hip/hip_runtime.h>
#include <stdint.h>

// BinHD: samples [8192,10000] f32 {0,1}, classes [1000,10000] f32 {0,1}
// out [8192,1000] f32 = Hamming = popcount(xor) over bit-packed rows (exact).
#define N_ROWS 8192
#define C_CLS  1000
#define D_DIM  10000
#define W64P   160            // u64 words per packed row, padded (157 used)
#define W32P   (W64P * 2)     // 320 u32 words per packed row
#define BSTR   132            // B LDS row stride (pads 128 -> kills conflicts)
#define CW     32             // chunk width in u32 words
#define NCHUNK 10             // 10 chunks x 32 words = 320

// ---------------------------------------------------------------------------
// Kernel 1: bit-pack via float4 + 4 wave ballots. One wave per row.
// ---------------------------------------------------------------------------
__global__ __launch_bounds__(256) void pack_kernel(
    const float* __restrict__ samples, const float* __restrict__ classes,
    unsigned long long* __restrict__ pA, unsigned long long* __restrict__ pB)
{
    int gwave = (blockIdx.x * 256 + threadIdx.x) >> 6;
    int lane  = threadIdx.x & 63;
    if (gwave >= N_ROWS + C_CLS) return;   // wave-uniform exit

    const float* src;
    unsigned long long* dst;
    if (gwave < N_ROWS) {
        src = samples + (size_t)gwave * D_DIM;
        dst = pA + (size_t)gwave * W64P;
    } else {
        int r = gwave - N_ROWS;
        src = classes + (size_t)r * D_DIM;
        dst = pB + (size_t)r * W64P;
    }

    #pragma unroll 4
    for (int it = 0; it < 39; ++it) {       // dims 0..9983 -> words 0..155
        float4 v = *(const float4*)(src + it * 256 + lane * 4);
        unsigned long long m0 = __ballot(v.x > 0.5f);
        unsigned long long m1 = __ballot(v.y > 0.5f);
        unsigned long long m2 = __ballot(v.z > 0.5f);
        unsigned long long m3 = __ballot(v.w > 0.5f);
        if (lane < 2) {
            ulonglong2 st;
            st.x = lane ? m2 : m0;
            st.y = lane ? m3 : m1;
            *(ulonglong2*)(dst + it * 4 + lane * 2) = st;
        }
    }
    {   // tail: dims 9984..9999 -> words 156..159 (zero-padded)
        float4 v = make_float4(0.f, 0.f, 0.f, 0.f);
        if (lane < 4) v = *(const float4*)(src + 9984 + lane * 4);
        unsigned long long m0 = __ballot(v.x > 0.5f);
        unsigned long long m1 = __ballot(v.y > 0.5f);
        unsigned long long m2 = __ballot(v.z > 0.5f);
        unsigned long long m3 = __ballot(v.w > 0.5f);
        if (lane < 2) {
            ulonglong2 st;
            st.x = lane ? m2 : m0;
            st.y = lane ? m3 : m1;
            *(ulonglong2*)(dst + 156 + lane * 2) = st;
        }
    }
}

// ---------------------------------------------------------------------------
// Kernel 2: Hamming GEMM. 128x128 tile, 256 thr, 8x8 acc/thread.
// R1's proven no-spill 2-barrier structure (load -> barrier -> LDS store ->
// barrier -> compute), but chunk widened 16->32 words: HALF the barriers.
// Single-buffered LDS:
//   As [128 rows][32 words], 16B-granule XOR swizzle keyed (row>>3)&7
//     -> fragment reads conflict-free (ly spreads all 8 bank-quads).
//   Bs transposed [32 kw][BSTR cols] -> uint4 read = 4 consecutive cols.
// NO register prefetch across compute, NO async LDS staging, NO
// launch_bounds min-waves arg (R2/R3/R4 all spilled acc[] to scratch).
// ---------------------------------------------------------------------------
__global__ __launch_bounds__(256) void hd_kernel(
    const uint32_t* __restrict__ pA, const uint32_t* __restrict__ pB,
    float* __restrict__ out)
{
    __shared__ __attribute__((aligned(16))) uint32_t As[128 * CW];
    __shared__ __attribute__((aligned(16))) uint32_t Bs[CW * BSTR];

    const int tid  = threadIdx.x;
    const int row0 = blockIdx.x * 128;
    const int col0 = blockIdx.y * 128;

    const int w    = tid >> 6;
    const int lane = tid & 63;
    const int lx   = lane & 7;
    const int ly   = lane >> 3;
    const int wx   = w & 1, wy = w >> 1;
    const int trow = wy * 64 + ly * 8;       // thread row base in 128-tile
    const int tcol = wx * 64 + lx * 4;       // thread col base (dense mapping)
    const int ka   = ly;                     // A read swizzle key = (row>>3)&7

    // staging: granule u = tid + 256*i (i=0..3); rr = u>>3 (row/col), gg = u&7
    uint32_t acc[8][8];
    #pragma unroll
    for (int r = 0; r < 8; ++r)
        #pragma unroll
        for (int c = 0; c < 8; ++c) acc[r][c] = 0;

    for (int ch = 0; ch < NCHUNK; ++ch) {
        // ---- global loads for this chunk ----
        uint4 av[4], bv[4];
        #pragma unroll
        for (int i = 0; i < 4; ++i) {
            int u  = tid + 256 * i;          // 0..1023
            int rr = u >> 3;                 // 0..127
            int gg = u & 7;                  // 16B granule 0..7
            av[i] = *(const uint4*)(pA + (size_t)(row0 + rr) * W32P + ch * CW + gg * 4);
            int gcol = col0 + rr;
            if (gcol < C_CLS)
                bv[i] = *(const uint4*)(pB + (size_t)gcol * W32P + ch * CW + gg * 4);
            else
                bv[i] = make_uint4(0u, 0u, 0u, 0u);
        }

        __syncthreads();   // previous chunk's LDS reads complete

        #pragma unroll
        for (int i = 0; i < 4; ++i) {
            int u  = tid + 256 * i;
            int rr = u >> 3;
            int gg = u & 7;
            // A: swizzled 16B-granule store
            *(uint4*)&As[rr * CW + ((gg ^ ((rr >> 3) & 7)) << 2)] = av[i];
            // B: transpose into [kw][col]
            Bs[(gg * 4 + 0) * BSTR + rr] = bv[i].x;
            Bs[(gg * 4 + 1) * BSTR + rr] = bv[i].y;
            Bs[(gg * 4 + 2) * BSTR + rr] = bv[i].z;
            Bs[(gg * 4 + 3) * BSTR + rr] = bv[i].w;
        }

        __syncthreads();   // LDS tile ready

        #pragma unroll
        for (int g = 0; g < 8; ++g) {
            uint4 a[8];
            #pragma unroll
            for (int r = 0; r < 8; ++r)
                a[r] = *(const uint4*)&As[(trow + r) * CW + ((g ^ ka) << 2)];
            #pragma unroll
            for (int j = 0; j < 4; ++j) {
                uint4 b0 = *(const uint4*)&Bs[(g * 4 + j) * BSTR + tcol];
                uint4 b1 = *(const uint4*)&Bs[(g * 4 + j) * BSTR + tcol + 32];
                #pragma unroll
                for (int r = 0; r < 8; ++r) {
                    uint32_t aw = (j == 0) ? a[r].x : (j == 1) ? a[r].y
                                : (j == 2) ? a[r].z : a[r].w;
                    acc[r][0] += __popc(aw ^ b0.x);
                    acc[r][1] += __popc(aw ^ b0.y);
                    acc[r][2] += __popc(aw ^ b0.z);
                    acc[r][3] += __popc(aw ^ b0.w);
                    acc[r][4] += __popc(aw ^ b1.x);
                    acc[r][5] += __popc(aw ^ b1.y);
                    acc[r][6] += __popc(aw ^ b1.z);
                    acc[r][7] += __popc(aw ^ b1.w);
                }
            }
        }
    }

    // ---- epilogue: dense float4 stores (lane-contiguous 128B lines) ----
    #pragma unroll
    for (int r = 0; r < 8; ++r) {
        int grow = row0 + trow + r;
        #pragma unroll
        for (int c4 = 0; c4 < 2; ++c4) {
            int gcol = col0 + tcol + c4 * 32;
            if (gcol < C_CLS) {
                float4 v = make_float4((float)acc[r][c4 * 4 + 0],
                                       (float)acc[r][c4 * 4 + 1],
                                       (float)acc[r][c4 * 4 + 2],
                                       (float)acc[r][c4 * 4 + 3]);
                *(float4*)(out + (size_t)grow * C_CLS + gcol) = v;
            }
        }
    }
}

extern "C" void kernel_launch(void* const* d_in, const int* in_sizes, int n_in,
                              void* d_out, int out_size, void* d_ws, size_t ws_size,
                              hipStream_t stream) {
    const float* samples = (const float*)d_in[0];   // [8192, 10000] f32
    const float* classes = (const float*)d_in[1];   // [1000, 10000] f32
    float* out = (float*)d_out;                     // [8192, 1000] f32

    unsigned long long* pA = (unsigned long long*)d_ws;          // 10.49 MB
    unsigned long long* pB = pA + (size_t)N_ROWS * W64P;         // +1.28 MB

    int waves  = N_ROWS + C_CLS;
    int blocks = (waves + 3) / 4;
    pack_kernel<<<blocks, 256, 0, stream>>>(samples, classes, pA, pB);

    dim3 grid(N_ROWS / 128, 8);              // 64 x 8 = 512 blocks (2/CU)
    hd_kernel<<<grid, 256, 0, stream>>>((const uint32_t*)pA, (const uint32_t*)pB, out);
}